// Round 6
// baseline (8660.718 us; speedup 1.0000x reference)
//
#include <hip/hip_runtime.h>
#include <math.h>

// Problem constants
#define RNN_B 64
#define RNN_T 512
#define RNN_IN 512
#define RNN_H 1024

// ws layout (float offsets):
//   0       h0buf[0]   (H*B = 65536 floats, layout [n][b])
//   65536   h1buf[0]
//   131072  h0buf[1]   <- zeroed each launch (initial h0_{-1})
//   196608  h1buf[1]   <- zeroed each launch (initial h1_{-1})
//   262144  flags[256] (u32 per block, monotonic phase counters)
//   262400  gen[8*16]  (u32, 8 padded generation copies, one line per bid&7)
// total needed: 262528 floats ~= 1.05 MB

__device__ __forceinline__ void fma16(float4 acc[4], const float4 w, const float4 h) {
  acc[0].x = fmaf(w.x, h.x, acc[0].x); acc[0].y = fmaf(w.x, h.y, acc[0].y);
  acc[0].z = fmaf(w.x, h.z, acc[0].z); acc[0].w = fmaf(w.x, h.w, acc[0].w);
  acc[1].x = fmaf(w.y, h.x, acc[1].x); acc[1].y = fmaf(w.y, h.y, acc[1].y);
  acc[1].z = fmaf(w.y, h.z, acc[1].z); acc[1].w = fmaf(w.y, h.w, acc[1].w);
  acc[2].x = fmaf(w.z, h.x, acc[2].x); acc[2].y = fmaf(w.z, h.y, acc[2].y);
  acc[2].z = fmaf(w.z, h.z, acc[2].z); acc[2].w = fmaf(w.z, h.w, acc[2].w);
  acc[3].x = fmaf(w.w, h.x, acc[3].x); acc[3].y = fmaf(w.w, h.y, acc[3].y);
  acc[3].z = fmaf(w.w, h.z, acc[3].z); acc[3].w = fmaf(w.w, h.w, acc[3].w);
}

// sum over the 4-way intra-wave k split (lane bits 3,4)
__device__ __forceinline__ void reduce4(float4 acc[4]) {
  #pragma unroll
  for (int m = 8; m <= 16; m <<= 1) {
    #pragma unroll
    for (int c = 0; c < 4; ++c) {
      acc[c].x += __shfl_xor(acc[c].x, m, 64);
      acc[c].y += __shfl_xor(acc[c].y, m, 64);
      acc[c].z += __shfl_xor(acc[c].z, m, 64);
      acc[c].w += __shfl_xor(acc[c].w, m, 64);
    }
  }
}

// tanh via v_exp/v_rcp: tanh(x) = sign(x) * (1 - 2/(exp2(2*log2e*|x|)+1)).
// Error ~1e-6 abs; overflow at large |x| gives inf -> t=1, correct limit.
__device__ __forceinline__ float fast_tanh(float x) {
  float ax = fabsf(x);
  float z  = __builtin_amdgcn_exp2f(ax * 2.8853900817779268f);  // 2*log2(e)
  float t  = 1.f - 2.f * __builtin_amdgcn_rcpf(z + 1.f);
  return __builtin_copysignf(t, x);
}

// Barrier v5: arrive / wait split. All stores RELAXED (h state uses
// LLC-coherent atomic stores -> no wbl2 anywhere). Caller guarantees a
// __syncthreads between the h stores and arrive (drains vmcnt).
__device__ __forceinline__ void barrier_arrive(unsigned* flags, unsigned target) {
  if (threadIdx.x == 0)
    __hip_atomic_store(flags + blockIdx.x, target, __ATOMIC_RELAXED,
                       __HIP_MEMORY_SCOPE_AGENT);
}

__device__ __forceinline__ void barrier_wait(unsigned* flags, unsigned* gen,
                                             unsigned target) {
  const int tid = threadIdx.x;
  const int bid = blockIdx.x;
  if (bid == 0) {
    if (tid < 64) {  // wave 0 gathers all 256 flags (4 per lane)
      for (;;) {
        bool ok = true;
        #pragma unroll
        for (int i = 0; i < 4; ++i) {
          unsigned v = __hip_atomic_load(flags + tid + 64 * i, __ATOMIC_RELAXED,
                                         __HIP_MEMORY_SCOPE_AGENT);
          ok &= (v >= target);
        }
        if (__all(ok)) break;
        __builtin_amdgcn_s_sleep(1);
      }
      if (tid < 8)  // publish 8 padded generation copies
        __hip_atomic_store(gen + tid * 16, target, __ATOMIC_RELAXED,
                           __HIP_MEMORY_SCOPE_AGENT);
    }
  } else if (tid == 0) {
    while (__hip_atomic_load(gen + (bid & 7) * 16, __ATOMIC_RELAXED,
                             __HIP_MEMORY_SCOPE_AGENT) < target) {
      __builtin_amdgcn_s_sleep(1);
    }
  }
  if (tid == 0)
    __builtin_amdgcn_fence(__ATOMIC_ACQUIRE, "agent");  // one inv per phase
  __syncthreads();
}

// ---------------------------------------------------------------------------
// Precompute: pre[n][b](t) = x[b,t,:]·W_ih0[n,:] + b_ih0[n] + b_hh0[n]
// Written into out as per-rnn-block slices of 256 contiguous floats.
// rnn block gbid owns n in [ (gbid>>1)*8, +8 ), b in [ (gbid&1)*32, +32 ),
// slot addr = ((gbid>>2)*T + t)*H + (gbid&3)*256, order [n&7][b&31].
// Slot is clobbered by the h1_t store at phase t+1, read at phase t -> safe.
// ---------------------------------------------------------------------------
__global__ __launch_bounds__(256) void pre_kernel(
    const float* __restrict__ x, const float* __restrict__ Wih0,
    const float* __restrict__ bih0, const float* __restrict__ bhh0,
    float* __restrict__ out)
{
  __shared__ float xs[64][68];  // [k][b], +4 pad keeps float4 alignment
  __shared__ float wl[64][68];  // [k][n]
  const int t  = blockIdx.y;
  const int n0 = blockIdx.x * 64;
  const int tid = threadIdx.x;
  const int tx = tid & 15;   // b-quad
  const int ty = tid >> 4;   // n-quad
  const int kf4 = tid & 15;  // staging: k float4 index
  const int row = tid >> 4;  // staging: row group

  float4 acc[4];
  acc[0] = acc[1] = acc[2] = acc[3] = make_float4(0.f, 0.f, 0.f, 0.f);

  for (int k0 = 0; k0 < RNN_IN; k0 += 64) {
    #pragma unroll
    for (int r = 0; r < 4; ++r) {
      const int rr = row + 16 * r;
      float4 v = *(const float4*)(x + ((size_t)rr * RNN_T + t) * RNN_IN + k0 + kf4 * 4);
      xs[kf4*4+0][rr] = v.x; xs[kf4*4+1][rr] = v.y;
      xs[kf4*4+2][rr] = v.z; xs[kf4*4+3][rr] = v.w;
      float4 w = *(const float4*)(Wih0 + (size_t)(n0 + rr) * RNN_IN + k0 + kf4 * 4);
      wl[kf4*4+0][rr] = w.x; wl[kf4*4+1][rr] = w.y;
      wl[kf4*4+2][rr] = w.z; wl[kf4*4+3][rr] = w.w;
    }
    __syncthreads();
    #pragma unroll 8
    for (int k = 0; k < 64; ++k) {
      float4 xv = *(const float4*)&xs[k][tx * 4];
      float4 wv = *(const float4*)&wl[k][ty * 4];
      fma16(acc, wv, xv);
    }
    __syncthreads();
  }

  // add bias; stage as xs[n_local][b]
  #pragma unroll
  for (int i = 0; i < 4; ++i) {
    const int n = n0 + ty * 4 + i;
    const float bi = bih0[n] + bhh0[n];
    xs[ty*4+i][tx*4+0] = acc[i].x + bi;
    xs[ty*4+i][tx*4+1] = acc[i].y + bi;
    xs[ty*4+i][tx*4+2] = acc[i].z + bi;
    xs[ty*4+i][tx*4+3] = acc[i].w + bi;
  }
  __syncthreads();
  #pragma unroll
  for (int rep = 0; rep < 4; ++rep) {
    const int idx = tid + 256 * rep;   // 0..1023
    const int nloc = idx >> 4;         // 0..63
    const int bq4 = idx & 15;          // b = bq4*4 .. +3 (b>>5 constant in quad)
    float4 o = *(const float4*)(&xs[nloc][bq4 * 4]);
    const int gbid = ((n0 + nloc) >> 3) * 2 + (bq4 >> 3);
    const int off  = (nloc & 7) * 32 + (bq4 & 7) * 4;
    const size_t dst = ((size_t)(gbid >> 2) * RNN_T + t) * RNN_H
                     + (size_t)(gbid & 3) * 256 + off;
    *(float4*)(out + dst) = o;
  }
}

// ---------------------------------------------------------------------------
// Persistent recurrence kernel (cooperative, 256 blocks x 1024 threads).
// Block (ng = bid>>1, bg = bid&1) owns cols n0 = ng*8 and batches b0 = bg*32.
// MERGED GEMV: one pass loads h0_{p-1} (feeds Whh0 AND Wih1 accs) + h1_{p-2}
// (feeds Whh1 acc) -- 32 f4 global loads/thread, single reduce stage.
// amdgpu_waves_per_eu(4,4): the cooperative launch pins occupancy at 1 block
// (16 waves = 4/SIMD) per CU, so tell the allocator min=max=4 waves/EU ->
// it may use the full 128 VGPRs instead of choosing 64 and SPILLING the
// merged loop (r5: WRITE_SIZE 3.7 GB of scratch churn at VGPR_Count=64).
// ---------------------------------------------------------------------------
__global__ __launch_bounds__(1024)
__attribute__((amdgpu_waves_per_eu(4, 4)))
void rnn_kernel(
    const float* __restrict__ Whh0, const float* __restrict__ Wih1,
    const float* __restrict__ Whh1, const float* __restrict__ bih1,
    const float* __restrict__ bhh1, float* __restrict__ out,
    float* __restrict__ hws)
{
  __shared__ float w0[RNN_H * 8];    // [k][8n] Whh0 rows, 32 KB
  __shared__ float w1[RNN_H * 16];   // [k][8n] Wih1 then Whh1 rows, 64 KB
  __shared__ float part0[16 * 256];  // per-wave L0 partials [w][nl*32+bl], 16 KB
  __shared__ float part1[16 * 256];  // per-wave L1 partials, 16 KB
  __shared__ float tile[256];        // h1 staging for out write, 1 KB

  const int tid = threadIdx.x;
  const int bid = blockIdx.x;
  const int n0 = (bid >> 1) * 8;
  const int b0 = (bid & 1) * 32;

  // stage this block's 8 weight rows of each matrix into LDS (once)
  for (int i = tid; i < 8 * RNN_H; i += 1024) {
    const int nl = i >> 10, k = i & 1023;
    w0[k * 8 + nl]             = Whh0[(size_t)(n0 + nl) * RNN_H + k];
    w1[k * 8 + nl]             = Wih1[(size_t)(n0 + nl) * RNN_H + k];
    w1[8 * RNN_H + k * 8 + nl] = Whh1[(size_t)(n0 + nl) * RNN_H + k];
  }
  float mybias = 0.f;
  if (tid < 256) mybias = bih1[n0 + (tid >> 5)] + bhh1[n0 + (tid >> 5)];
  __syncthreads();

  const int wav  = tid >> 6;         // 0..15
  const int lane = tid & 63;
  const int nh   = lane >> 5;        // n-half (0..1)
  const int kq   = (lane >> 3) & 3;  // intra-wave k split (0..3)
  const int bq   = lane & 7;         // b quad within slice (0..7)
  const int kbase = wav * 4 + kq;    // k = j*64 + kbase
  const int hoff = kbase * RNN_B + b0 + bq * 4;   // into h bufs [k][64]
  const int woff = kbase * 8 + nh * 4;            // into w LDS [k][8]

  unsigned* flags = (unsigned*)(hws + 262144);
  unsigned* gen   = (unsigned*)(hws + 262400);
  float* h0buf[2] = { hws,         hws + 131072 };
  float* h1buf[2] = { hws + 65536, hws + 196608 };
  const int houtoff = (n0 + (tid >> 5)) * RNN_B + b0 + (tid & 31);

  float preval = 0.f, nextpre = 0.f;
  if (tid < 256)
    preval = out[(size_t)(bid >> 2) * RNN_T * RNN_H + (size_t)(bid & 3) * 256 + tid];

  for (int p = 0; p <= RNN_T; ++p) {
    // prefetch next phase's x-contribution early (overlaps the GEMV; register
    // survives the barrier invalidate; slot clobbered only at phase p+2)
    if (tid < 256 && p + 1 < RNN_T)
      nextpre = out[((size_t)(bid >> 2) * RNN_T + (p + 1)) * RNN_H
                    + (size_t)(bid & 3) * 256 + tid];

    float4 a0[4], a1[4];
    a0[0] = a0[1] = a0[2] = a0[3] = make_float4(0.f, 0.f, 0.f, 0.f);
    a1[0] = a1[1] = a1[2] = a1[3] = make_float4(0.f, 0.f, 0.f, 0.f);

    if (p >= 1 && p < RNN_T) {
      // merged pass: h0_{p-1} feeds a0 (Whh0) and a1 (Wih1); h1_{p-2} feeds
      // a1 (Whh1). h0buf[(p+1)&1] == h0buf[(p-1)&1] == h0_{p-1}.
      const float* hc  = h0buf[(p + 1) & 1] + hoff;
      const float* h1p = h1buf[p & 1]       + hoff;
      const float* wp0 = w0 + woff;
      const float* wpa = w1 + woff;
      const float* wpb = w1 + 8 * RNN_H + woff;
      #pragma unroll
      for (int j = 0; j < 16; ++j) {            // k = j*64 + kbase
        float4 h0v = *(const float4*)(hc  + j * 64 * RNN_B);
        float4 h1v = *(const float4*)(h1p + j * 64 * RNN_B);
        float4 wv0 = *(const float4*)(wp0 + j * 64 * 8);
        float4 wva = *(const float4*)(wpa + j * 64 * 8);
        float4 wvb = *(const float4*)(wpb + j * 64 * 8);
        fma16(a0, wv0, h0v);
        fma16(a1, wva, h0v);
        fma16(a1, wvb, h1v);
      }
    } else if (p == 0) {
      const float* hc  = h0buf[1] + hoff;       // zeros
      const float* wp0 = w0 + woff;
      #pragma unroll
      for (int j = 0; j < 16; ++j) {
        float4 h0v = *(const float4*)(hc + j * 64 * RNN_B);
        float4 wv0 = *(const float4*)(wp0 + j * 64 * 8);
        fma16(a0, wv0, h0v);
      }
    } else {  // p == RNN_T: layer-1 only
      const float* h0t = h0buf[(p + 1) & 1] + hoff;  // h0_{T-1}
      const float* h1p = h1buf[p & 1]       + hoff;  // h1_{T-2}
      const float* wpa = w1 + woff;
      const float* wpb = w1 + 8 * RNN_H + woff;
      #pragma unroll
      for (int j = 0; j < 16; ++j) {
        float4 h0v = *(const float4*)(h0t + j * 64 * RNN_B);
        float4 h1v = *(const float4*)(h1p + j * 64 * RNN_B);
        float4 wva = *(const float4*)(wpa + j * 64 * 8);
        float4 wvb = *(const float4*)(wpb + j * 64 * 8);
        fma16(a1, wva, h0v);
        fma16(a1, wvb, h1v);
      }
    }

    if (p < RNN_T) {
      reduce4(a0);
      if ((lane & 24) == 0) {                   // kq == 0: lane = nh*32 + bq
        #pragma unroll
        for (int c = 0; c < 4; ++c)
          *(float4*)(part0 + wav * 256 + (nh * 4 + c) * 32 + bq * 4) = a0[c];
      }
    }
    if (p >= 1) {
      reduce4(a1);
      if ((lane & 24) == 0) {
        #pragma unroll
        for (int c = 0; c < 4; ++c)
          *(float4*)(part1 + wav * 256 + (nh * 4 + c) * 32 + bq * 4) = a1[c];
      }
    }
    __syncthreads();
    // final 16-way partial sums + tanh + LLC-coherent state stores
    if (tid < 256) {
      if (p < RNN_T) {
        float s = preval;
        #pragma unroll
        for (int w = 0; w < 16; ++w) s += part0[w * 256 + tid];
        __hip_atomic_store(&h0buf[p & 1][houtoff], fast_tanh(s), __ATOMIC_RELAXED,
                           __HIP_MEMORY_SCOPE_AGENT);
      }
      if (p >= 1) {
        float s = mybias;
        #pragma unroll
        for (int w = 0; w < 16; ++w) s += part1[w * 256 + tid];
        float v = fast_tanh(s);
        __hip_atomic_store(&h1buf[(p - 1) & 1][houtoff], v, __ATOMIC_RELAXED,
                           __HIP_MEMORY_SCOPE_AGENT);
        tile[tid] = v;
      }
      preval = nextpre;
    }
    __syncthreads();  // drains the h atomic stores (vmcnt 0) + publishes tile

    // EARLY ARRIVE: h state of this phase is at the coherence point.
    if (p < RNN_T) barrier_arrive(flags, (unsigned)(p + 1));

    // wait-window work: out-write (read by nobody until kernel end)
    if (p >= 1 && tid < 64) {  // out[b][t][n0..n0+7]: 2 float4 per b
      const int b = tid >> 1, half = tid & 1;
      float4 o;
      o.x = tile[(half * 4 + 0) * 32 + b];
      o.y = tile[(half * 4 + 1) * 32 + b];
      o.z = tile[(half * 4 + 2) * 32 + b];
      o.w = tile[(half * 4 + 3) * 32 + b];
      *(float4*)(out + ((size_t)(b0 + b) * RNN_T + (p - 1)) * RNN_H + n0 + half * 4) = o;
    }

    // LATE WAIT
    if (p < RNN_T) barrier_wait(flags, gen, (unsigned)(p + 1));
  }

  // h_final tail: out[BTH + l*B*H + b*H + n]; finals live in buf index 1.
  // Atomic loads read the LLC truth (own L2 could hold a stale line).
  if (tid < 512) {
    const int l   = tid >> 8;
    const int idx = tid & 255;
    const int nl  = idx >> 5, bl = idx & 31;
    const float* hf = (l == 0) ? (hws + 131072) : (hws + 196608);
    float v = __hip_atomic_load(hf + (size_t)(n0 + nl) * RNN_B + b0 + bl,
                                __ATOMIC_RELAXED, __HIP_MEMORY_SCOPE_AGENT);
    out[(size_t)RNN_B * RNN_T * RNN_H + ((size_t)l * RNN_B + b0 + bl) * RNN_H + n0 + nl]
        = v;
  }
}

extern "C" void kernel_launch(void* const* d_in, const int* in_sizes, int n_in,
                              void* d_out, int out_size, void* d_ws, size_t ws_size,
                              hipStream_t stream) {
  (void)in_sizes; (void)n_in; (void)out_size; (void)ws_size;
  const float* x    = (const float*)d_in[0];
  const float* Wih0 = (const float*)d_in[1];
  const float* Whh0 = (const float*)d_in[2];
  const float* bih0 = (const float*)d_in[3];
  const float* bhh0 = (const float*)d_in[4];
  const float* Wih1 = (const float*)d_in[5];
  const float* Whh1 = (const float*)d_in[6];
  const float* bih1 = (const float*)d_in[7];
  const float* bhh1 = (const float*)d_in[8];
  float* out = (float*)d_out;
  float* hws = (float*)d_ws;

  // zero initial h buffers (index 1) + flags + gen (ws is 0xAA-poisoned)
  hipMemsetAsync(hws + 131072, 0, (131072 + 256 + 128) * sizeof(float), stream);

  dim3 pg(16, 512);
  pre_kernel<<<pg, 256, 0, stream>>>(x, Wih0, bih0, bhh0, out);

  void* args[] = { (void*)&Whh0, (void*)&Wih1, (void*)&Whh1,
                   (void*)&bih1, (void*)&bhh1, (void*)&out, (void*)&hws };
  hipLaunchCooperativeKernel((const void*)rnn_kernel, dim3(256), dim3(1024),
                             args, 0, stream);
}

// Round 7
// 7904.975 us; speedup vs baseline: 1.0956x; 1.0956x over previous
//
#include <hip/hip_runtime.h>
#include <math.h>

// Problem constants
#define RNN_B 64
#define RNN_T 512
#define RNN_IN 512
#define RNN_H 1024

// ws layout (float offsets):
//   0       h0buf[0]   (H*B = 65536 floats, layout [n][b])
//   65536   h1buf[0]
//   131072  h0buf[1]   <- zeroed each launch (initial h0_{-1})
//   196608  h1buf[1]   <- zeroed each launch (initial h1_{-1})
//   262144  f0[256]    (u32 per block: h0 phases completed)
//   262400  f1[256]    (u32 per block: h1 phases completed)
// total 262656 floats ~= 1.05 MB

__device__ __forceinline__ void fma16(float4 acc[4], const float4 w, const float4 h) {
  acc[0].x = fmaf(w.x, h.x, acc[0].x); acc[0].y = fmaf(w.x, h.y, acc[0].y);
  acc[0].z = fmaf(w.x, h.z, acc[0].z); acc[0].w = fmaf(w.x, h.w, acc[0].w);
  acc[1].x = fmaf(w.y, h.x, acc[1].x); acc[1].y = fmaf(w.y, h.y, acc[1].y);
  acc[1].z = fmaf(w.y, h.z, acc[1].z); acc[1].w = fmaf(w.y, h.w, acc[1].w);
  acc[2].x = fmaf(w.z, h.x, acc[2].x); acc[2].y = fmaf(w.z, h.y, acc[2].y);
  acc[2].z = fmaf(w.z, h.z, acc[2].z); acc[2].w = fmaf(w.z, h.w, acc[2].w);
  acc[3].x = fmaf(w.w, h.x, acc[3].x); acc[3].y = fmaf(w.w, h.y, acc[3].y);
  acc[3].z = fmaf(w.w, h.z, acc[3].z); acc[3].w = fmaf(w.w, h.w, acc[3].w);
}

// sum over the 4-way intra-wave k split (lane bits 3,4)
__device__ __forceinline__ void reduce4(float4 acc[4]) {
  #pragma unroll
  for (int m = 8; m <= 16; m <<= 1) {
    #pragma unroll
    for (int c = 0; c < 4; ++c) {
      acc[c].x += __shfl_xor(acc[c].x, m, 64);
      acc[c].y += __shfl_xor(acc[c].y, m, 64);
      acc[c].z += __shfl_xor(acc[c].z, m, 64);
      acc[c].w += __shfl_xor(acc[c].w, m, 64);
    }
  }
}

// tanh via v_exp/v_rcp: tanh(x) = sign(x)*(1 - 2/(exp2(2*log2e*|x|)+1)).
__device__ __forceinline__ float fast_tanh(float x) {
  float ax = fabsf(x);
  float z  = __builtin_amdgcn_exp2f(ax * 2.8853900817779268f);  // 2*log2(e)
  float t  = 1.f - 2.f * __builtin_amdgcn_rcpf(z + 1.f);
  return __builtin_copysignf(t, x);
}

// Pipelined split-flag sync (v7). All-poll, all-relaxed, monotonic flags;
// optional single acquire fence (L2 invalidate) per phase. Wave 0 polls all
// 256 flags (4/lane); ends with __syncthreads so it doubles as a block
// barrier wherever it is placed.
__device__ __forceinline__ void wait_ge(unsigned* arr, int target, bool fence) {
  const int tid = threadIdx.x;
  if (tid < 64 && target > 0) {
    for (;;) {
      bool ok = true;
      #pragma unroll
      for (int i = 0; i < 4; ++i) {
        unsigned v = __hip_atomic_load(arr + tid + 64 * i, __ATOMIC_RELAXED,
                                       __HIP_MEMORY_SCOPE_AGENT);
        ok &= ((int)v >= target);
      }
      if (__all(ok)) break;
      __builtin_amdgcn_s_sleep(1);
    }
  }
  if (fence && tid == 0)
    __builtin_amdgcn_fence(__ATOMIC_ACQUIRE, "agent");
  __syncthreads();
}

__device__ __forceinline__ void post(unsigned* arr, unsigned v) {
  if (threadIdx.x == 0)
    __hip_atomic_store(arr + blockIdx.x, v, __ATOMIC_RELAXED,
                       __HIP_MEMORY_SCOPE_AGENT);
}

// ---------------------------------------------------------------------------
// Precompute: pre[n][b](t) = x[b,t,:]·W_ih0[n,:] + b_ih0[n] + b_hh0[n]
// Written into out as per-rnn-block slices of 256 contiguous floats.
// rnn block gbid owns n in [ (gbid>>1)*8, +8 ), b in [ (gbid&1)*32, +32 ),
// slot addr = ((gbid>>2)*T + t)*H + (gbid&3)*256, order [n&7][b&31].
// Slot is clobbered by the h1_t out-write at phase t+1, read at phase t.
// ---------------------------------------------------------------------------
__global__ __launch_bounds__(256) void pre_kernel(
    const float* __restrict__ x, const float* __restrict__ Wih0,
    const float* __restrict__ bih0, const float* __restrict__ bhh0,
    float* __restrict__ out)
{
  __shared__ float xs[64][68];  // [k][b], +4 pad keeps float4 alignment
  __shared__ float wl[64][68];  // [k][n]
  const int t  = blockIdx.y;
  const int n0 = blockIdx.x * 64;
  const int tid = threadIdx.x;
  const int tx = tid & 15;   // b-quad
  const int ty = tid >> 4;   // n-quad
  const int kf4 = tid & 15;  // staging: k float4 index
  const int row = tid >> 4;  // staging: row group

  float4 acc[4];
  acc[0] = acc[1] = acc[2] = acc[3] = make_float4(0.f, 0.f, 0.f, 0.f);

  for (int k0 = 0; k0 < RNN_IN; k0 += 64) {
    #pragma unroll
    for (int r = 0; r < 4; ++r) {
      const int rr = row + 16 * r;
      float4 v = *(const float4*)(x + ((size_t)rr * RNN_T + t) * RNN_IN + k0 + kf4 * 4);
      xs[kf4*4+0][rr] = v.x; xs[kf4*4+1][rr] = v.y;
      xs[kf4*4+2][rr] = v.z; xs[kf4*4+3][rr] = v.w;
      float4 w = *(const float4*)(Wih0 + (size_t)(n0 + rr) * RNN_IN + k0 + kf4 * 4);
      wl[kf4*4+0][rr] = w.x; wl[kf4*4+1][rr] = w.y;
      wl[kf4*4+2][rr] = w.z; wl[kf4*4+3][rr] = w.w;
    }
    __syncthreads();
    #pragma unroll 8
    for (int k = 0; k < 64; ++k) {
      float4 xv = *(const float4*)&xs[k][tx * 4];
      float4 wv = *(const float4*)&wl[k][ty * 4];
      fma16(acc, wv, xv);
    }
    __syncthreads();
  }

  // add bias; stage as xs[n_local][b]
  #pragma unroll
  for (int i = 0; i < 4; ++i) {
    const int n = n0 + ty * 4 + i;
    const float bi = bih0[n] + bhh0[n];
    xs[ty*4+i][tx*4+0] = acc[i].x + bi;
    xs[ty*4+i][tx*4+1] = acc[i].y + bi;
    xs[ty*4+i][tx*4+2] = acc[i].z + bi;
    xs[ty*4+i][tx*4+3] = acc[i].w + bi;
  }
  __syncthreads();
  #pragma unroll
  for (int rep = 0; rep < 4; ++rep) {
    const int idx = tid + 256 * rep;   // 0..1023
    const int nloc = idx >> 4;         // 0..63
    const int bq4 = idx & 15;
    float4 o = *(const float4*)(&xs[nloc][bq4 * 4]);
    const int gbid = ((n0 + nloc) >> 3) * 2 + (bq4 >> 3);
    const int off  = (nloc & 7) * 32 + (bq4 & 7) * 4;
    const size_t dst = ((size_t)(gbid >> 2) * RNN_T + t) * RNN_H
                     + (size_t)(gbid & 3) * 256 + off;
    *(float4*)(out + dst) = o;
  }
}

// ---------------------------------------------------------------------------
// Persistent recurrence kernel (cooperative, 256 blocks x 1024 threads).
// Block (ng = bid>>1, bg = bid&1) owns cols n0 = ng*8 and batches b0 = bg*32.
// r4's proven no-spill two-pass GEMVs. v7 pipelined sync:
//   top:  wait f0 >= p (h0_{p-1} ready) + fence   [pre-satisfied: posted
//         mid-phase by everyone -> L1 of phase p-1 hid the hop]
//   mid:  wait f1 >= p (h1_{p-2} ready AND anti-dep: everyone done reading
//         h0_{p-2}/h1_{p-3}) -- doubles as the part0 barrier; the L0 GEMV
//         duration hides this hop.
//   post f0=p+1 right after the h0-store drain; post f1=p+1 after h1 drain.
// Race audit (2-slot parity buffers): h0_p store needs readers of h0_{p-2}
// done = L0@p-1 (f0>=p at top) + L1@p-1 (f1>=p at mid) -> covered. h1_{p-1}
// store overwrites h1_{p-3}, read by L1@p-1 (f1>=p at mid) -> covered.
// Max block skew is bounded by the mid-wait; monotonic flags -> no deadlock.
// ---------------------------------------------------------------------------
__global__ __launch_bounds__(1024) void rnn_kernel(
    const float* __restrict__ Whh0, const float* __restrict__ Wih1,
    const float* __restrict__ Whh1, const float* __restrict__ bih1,
    const float* __restrict__ bhh1, float* __restrict__ out,
    float* __restrict__ hws)
{
  __shared__ float w0[RNN_H * 8];    // [k][8n] Whh0 rows, 32 KB
  __shared__ float w1[RNN_H * 16];   // [k][8n] Wih1 then Whh1 rows, 64 KB
  __shared__ float part0[16 * 256];  // per-wave L0 partials, 16 KB
  __shared__ float part1[16 * 256];  // per-wave L1 partials, 16 KB
  __shared__ float tile[256];        // h1 staging for out write, 1 KB

  const int tid = threadIdx.x;
  const int bid = blockIdx.x;
  const int n0 = (bid >> 1) * 8;
  const int b0 = (bid & 1) * 32;

  // stage this block's 8 weight rows of each matrix into LDS (once)
  for (int i = tid; i < 8 * RNN_H; i += 1024) {
    const int nl = i >> 10, k = i & 1023;
    w0[k * 8 + nl]             = Whh0[(size_t)(n0 + nl) * RNN_H + k];
    w1[k * 8 + nl]             = Wih1[(size_t)(n0 + nl) * RNN_H + k];
    w1[8 * RNN_H + k * 8 + nl] = Whh1[(size_t)(n0 + nl) * RNN_H + k];
  }
  float mybias = 0.f;
  if (tid < 256) mybias = bih1[n0 + (tid >> 5)] + bhh1[n0 + (tid >> 5)];
  __syncthreads();

  const int wav  = tid >> 6;         // 0..15
  const int lane = tid & 63;
  const int nh   = lane >> 5;        // n-half (0..1)
  const int bq   = lane & 7;         // b quad within slice (0..7)
  const int kq   = (lane >> 3) & 3;  // intra-wave k split (0..3)
  const int kbase = wav * 4 + kq;    // k = j*64 + kbase
  const int hoff = kbase * RNN_B + b0 + bq * 4;   // into h bufs [k][64]
  const int woff = kbase * 8 + nh * 4;            // into w LDS [k][8]

  unsigned* f0 = (unsigned*)(hws + 262144);
  unsigned* f1 = (unsigned*)(hws + 262400);
  float* h0buf[2] = { hws,         hws + 131072 };
  float* h1buf[2] = { hws + 65536, hws + 196608 };
  const int houtoff = (n0 + (tid >> 5)) * RNN_B + b0 + (tid & 31);

  float preval = 0.f, nextpre = 0.f;
  if (tid < 256)
    preval = out[(size_t)(bid >> 2) * RNN_T * RNN_H + (size_t)(bid & 3) * 256 + tid];

  for (int p = 0; p <= RNN_T; ++p) {
    // ---- top wait: h0_{p-1} available; one L2-invalidate per phase ----
    wait_ge(f0, p, true);
    if (tid < 256 && p + 1 < RNN_T)
      nextpre = out[((size_t)(bid >> 2) * RNN_T + (p + 1)) * RNN_H
                    + (size_t)(bid & 3) * 256 + tid];

    // ---- L0 GEMV: h0_p = tanh(pre + h0_{p-1} @ Whh0^T) ----
    if (p < RNN_T) {
      const float* hp = h0buf[(p + 1) & 1] + hoff;
      const float* wp = w0 + woff;
      float4 acc[4];
      acc[0] = acc[1] = acc[2] = acc[3] = make_float4(0.f, 0.f, 0.f, 0.f);
      #pragma unroll
      for (int j = 0; j < 16; ++j) {            // k = j*64 + kbase
        float4 hv = *(const float4*)(hp + j * 64 * RNN_B);
        float4 wv = *(const float4*)(wp + j * 64 * 8);
        fma16(acc, wv, hv);
      }
      reduce4(acc);
      if ((lane & 24) == 0) {                   // kq == 0: lane = nh*32 + bq
        #pragma unroll
        for (int c = 0; c < 4; ++c)
          *(float4*)(part0 + wav * 256 + (nh * 4 + c) * 32 + bq * 4) = acc[c];
      }
    }

    // ---- mid wait: f1 >= p (h1_{p-2} ready + anti-deps); also the part0
    // barrier. The L0 GEMV above hides this hop. No fence: invalidated lines
    // from the top fence were not re-cached for h1/h0_{p-2} addresses.
    wait_ge(f1, p, false);

    if (p < RNN_T && tid < 256) {
      float s = preval;
      #pragma unroll
      for (int w = 0; w < 16; ++w) s += part0[w * 256 + tid];
      __hip_atomic_store(&h0buf[p & 1][houtoff], fast_tanh(s), __ATOMIC_RELAXED,
                         __HIP_MEMORY_SCOPE_AGENT);
    }
    if (tid < 256) preval = nextpre;
    __syncthreads();                            // drain h0 stores (vmcnt 0)
    if (p < RNN_T) post(f0, (unsigned)(p + 1)); // EARLY h0 publish
    if (p == 0)   post(f1, 1u);                 // vacuous L1 of phase 0

    // ---- L1 GEMV: h1_t = tanh(h0_t@Wih1^T + h1_{t-1}@Whh1^T + b), t=p-1 ----
    if (p >= 1) {
      const int t = p - 1;
      const float* h0t = h0buf[t & 1]       + hoff;
      const float* h1p = h1buf[(t + 1) & 1] + hoff;
      const float* wpa = w1 + woff;
      const float* wpb = w1 + 8 * RNN_H + woff;
      float4 acc[4];
      acc[0] = acc[1] = acc[2] = acc[3] = make_float4(0.f, 0.f, 0.f, 0.f);
      #pragma unroll
      for (int j = 0; j < 16; ++j) {
        float4 hv0 = *(const float4*)(h0t + j * 64 * RNN_B);
        float4 wv0 = *(const float4*)(wpa + j * 64 * 8);
        float4 hv1 = *(const float4*)(h1p + j * 64 * RNN_B);
        float4 wv1 = *(const float4*)(wpb + j * 64 * 8);
        fma16(acc, wv0, hv0);
        fma16(acc, wv1, hv1);
      }
      reduce4(acc);
      if ((lane & 24) == 0) {
        #pragma unroll
        for (int c = 0; c < 4; ++c)
          *(float4*)(part1 + wav * 256 + (nh * 4 + c) * 32 + bq * 4) = acc[c];
      }
      __syncthreads();                          // part1 ready
      if (tid < 256) {
        float s = mybias;
        #pragma unroll
        for (int w = 0; w < 16; ++w) s += part1[w * 256 + tid];
        float v = fast_tanh(s);
        __hip_atomic_store(&h1buf[t & 1][houtoff], v, __ATOMIC_RELAXED,
                           __HIP_MEMORY_SCOPE_AGENT);
        tile[tid] = v;
      }
      __syncthreads();                          // drain h1 stores + tile
      post(f1, (unsigned)(p + 1));
      if (tid < 64) {  // out[b][t][n0..n0+7]: 2 float4 per b (plain cached)
        const int b = tid >> 1, half = tid & 1;
        float4 o;
        o.x = tile[(half * 4 + 0) * 32 + b];
        o.y = tile[(half * 4 + 1) * 32 + b];
        o.z = tile[(half * 4 + 2) * 32 + b];
        o.w = tile[(half * 4 + 3) * 32 + b];
        *(float4*)(out + ((size_t)(b0 + b) * RNN_T + t) * RNN_H + n0 + half * 4) = o;
      }
    }
  }

  // h_final tail: own-block slice only; finals live in slot 1 (511 odd).
  // Atomic loads: own L2 may hold stale lines for those addresses.
  if (tid < 512) {
    const int l   = tid >> 8;
    const int idx = tid & 255;
    const int nl  = idx >> 5, bl = idx & 31;
    const float* hf = (l == 0) ? (hws + 131072) : (hws + 196608);
    float v = __hip_atomic_load(hf + (size_t)(n0 + nl) * RNN_B + b0 + bl,
                                __ATOMIC_RELAXED, __HIP_MEMORY_SCOPE_AGENT);
    out[(size_t)RNN_B * RNN_T * RNN_H + ((size_t)l * RNN_B + b0 + bl) * RNN_H + n0 + nl]
        = v;
  }
}

extern "C" void kernel_launch(void* const* d_in, const int* in_sizes, int n_in,
                              void* d_out, int out_size, void* d_ws, size_t ws_size,
                              hipStream_t stream) {
  (void)in_sizes; (void)n_in; (void)out_size; (void)ws_size;
  const float* x    = (const float*)d_in[0];
  const float* Wih0 = (const float*)d_in[1];
  const float* Whh0 = (const float*)d_in[2];
  const float* bih0 = (const float*)d_in[3];
  const float* bhh0 = (const float*)d_in[4];
  const float* Wih1 = (const float*)d_in[5];
  const float* Whh1 = (const float*)d_in[6];
  const float* bih1 = (const float*)d_in[7];
  const float* bhh1 = (const float*)d_in[8];
  float* out = (float*)d_out;
  float* hws = (float*)d_ws;

  // zero initial h buffers (slot 1) + f0 + f1 (ws is 0xAA-poisoned)
  hipMemsetAsync(hws + 131072, 0, (131072 + 512) * sizeof(float), stream);

  dim3 pg(16, 512);
  pre_kernel<<<pg, 256, 0, stream>>>(x, Wih0, bih0, bhh0, out);

  void* args[] = { (void*)&Whh0, (void*)&Wih1, (void*)&Whh1,
                   (void*)&bih1, (void*)&bhh1, (void*)&out, (void*)&hws };
  hipLaunchCooperativeKernel((const void*)rnn_kernel, dim3(256), dim3(1024),
                             args, 0, stream);
}